// Round 14
// baseline (777.667 us; speedup 1.0000x reference)
//
#include <hip/hip_runtime.h>

typedef float f32x4 __attribute__((ext_vector_type(4)));

#define TSTEPS 500
#define BDIM 64
#define CIN 512
#define COUT 512
#define MTOT (TSTEPS * BDIM)   // 32000
#define NCH (BDIM * CIN)       // 32768
#define SNEUR (BDIM * COUT)    // 32768
#define OUTN ((size_t)TSTEPS * SNEUR + SNEUR)

#define AL64 0.95122942450071400909   // math.exp(-0.001/0.02), f64
#define BL64 (1.0 - AL64)

__global__ __launch_bounds__(256) void fill_const_f32(
    float* __restrict__ p, size_t n, float c) {
  size_t i = (size_t)blockIdx.x * 256 + threadIdx.x;
  const size_t stride = (size_t)gridDim.x * 256;
  for (; i < n; i += stride) p[i] = c;
}

__device__ __forceinline__ void gll16(const float* g, float* l) {
  __builtin_amdgcn_global_load_lds(
      (const __attribute__((address_space(1))) void*)g,
      (__attribute__((address_space(3))) void*)l, 16, 0, 0);
}

// ---------------------------------------------------------------------------
// f32 trace scan (np-exact): tr = fl(fl(a*tr) + x)   [proven R13]
// ---------------------------------------------------------------------------
__global__ __launch_bounds__(256) void trace32(
    const float* __restrict__ X, float* __restrict__ TR,
    const float* __restrict__ alpha) {
  const int j = blockIdx.x * 256 + threadIdx.x;  // b*512 + ci
  const float a = fminf(fmaxf(alpha[0], 0.0f), 0.9999f);
  float tr = 0.0f;
#pragma unroll 10
  for (int t = 0; t < TSTEPS; ++t) {
    float x = X[(size_t)t * NCH + j];
    tr = __fadd_rn(__fmul_rn(a, tr), x);
    TR[(size_t)t * NCH + j] = tr;
  }
}

// ---------------------------------------------------------------------------
// Fused CUR = (X@W) + (TR@W); reduction order IDENTICAL to R13 (head chain
// k<384, tail chain k>=384, combine fadd(fadd(xH,xT), fadd(tH,tT))).
// New structure: BM=64 x BN=128 tile, BK=16, double-buffered LDS staged via
// global_load_lds(16B); A k-groups XOR-swizzled on the GLOBAL source
// (linear LDS dest per rule #21), un-swizzled on the LDS read.
// Per thread: 4 rows x 8 cols x 4 chain-sets = 128 acc VGPRs.
// ---------------------------------------------------------------------------
__global__ __launch_bounds__(256, 2) void gemm_fused2(
    const float* __restrict__ X, const float* __restrict__ TR,
    const float* __restrict__ W, float* __restrict__ CUR) {
  __shared__ __align__(16) float Ax[2][1024];  // [buf][64 rows x 16 k]
  __shared__ __align__(16) float At[2][1024];
  __shared__ __align__(16) float Bs[2][2048];  // [buf][16 k x 128 n]
  const int tid = threadIdx.x;
  const int ty = tid >> 4, tx = tid & 15;      // out: rows ty*4.., cols tx*4 & 64+tx*4
  const int bm = blockIdx.y * 64, bn = blockIdx.x * 128;
  const int wb = (tid & 192) * 4;              // wave-uniform LDS float offset

  // staging sources (per-lane 16B); A source pre-swizzled: ags = ag ^ ((row>>2)&3)
  const int arow = tid >> 2, ag = tid & 3;
  const int ags = ag ^ ((arow >> 2) & 3);
  const float* sx = X + (size_t)(bm + arow) * CIN + ags * 4;
  const float* st = TR + (size_t)(bm + arow) * CIN + ags * 4;
  const int brow0 = tid >> 5, bcg = (tid & 31) * 4;  // slot q=0
  const float* sb0 = W + (size_t)brow0 * COUT + bn + bcg;
  const float* sb1 = W + (size_t)(8 + brow0) * COUT + bn + bcg;  // slot q=1

  float xH[4][8] = {{0.0f}}, xT[4][8] = {{0.0f}};
  float tH[4][8] = {{0.0f}}, tT[4][8] = {{0.0f}};

  auto stage = [&](int b) {
    gll16(sx, &Ax[b][wb]);
    gll16(st, &At[b][wb]);
    gll16(sb0, &Bs[b][wb]);
    gll16(sb1, &Bs[b][1024 + wb]);
    sx += 16; st += 16;                 // next 16 k
    sb0 += 16 * COUT; sb1 += 16 * COUT; // next 16 k rows
  };

  const int sw = ty & 3;  // A read-side un-swizzle (== (m>>2)&3 for m=ty*4+i)

#define COMPUTE(b, AX, AT)                                                   \
  {                                                                          \
    const float* axp = Ax[b];                                                \
    const float* atp = At[b];                                                \
    const float* bsp = Bs[b];                                                \
    _Pragma("unroll") for (int kg = 0; kg < 4; ++kg) {                       \
      const int G = (kg ^ sw) * 4;                                           \
      f32x4 avx[4], avt[4];                                                  \
      _Pragma("unroll") for (int i = 0; i < 4; ++i) {                        \
        avx[i] = *(const f32x4*)&axp[(ty * 4 + i) * 16 + G];                 \
        avt[i] = *(const f32x4*)&atp[(ty * 4 + i) * 16 + G];                 \
      }                                                                      \
      _Pragma("unroll") for (int k2 = 0; k2 < 4; ++k2) {                     \
        f32x4 bL = *(const f32x4*)&bsp[(kg * 4 + k2) * 128 + tx * 4];        \
        f32x4 bH = *(const f32x4*)&bsp[(kg * 4 + k2) * 128 + 64 + tx * 4];   \
        _Pragma("unroll") for (int i = 0; i < 4; ++i)                        \
          _Pragma("unroll") for (int j = 0; j < 4; ++j) {                    \
            AX[i][j]     = fmaf(avx[i][k2], bL[j], AX[i][j]);                \
            AX[i][4 + j] = fmaf(avx[i][k2], bH[j], AX[i][4 + j]);            \
            AT[i][j]     = fmaf(avt[i][k2], bL[j], AT[i][j]);                \
            AT[i][4 + j] = fmaf(avt[i][k2], bH[j], AT[i][4 + j]);            \
          }                                                                  \
      }                                                                      \
    }                                                                        \
  }

  stage(0);
  int buf = 0;
  for (int kt = 0; kt < 32; ++kt) {
    __syncthreads();               // drains vmcnt -> buf[buf] staged
    if (kt < 31) stage(buf ^ 1);   // async prefetch next tile
    if (kt < 24) {
      COMPUTE(buf, xH, tH);        // head: k in [0,384)
    } else {
      COMPUTE(buf, xT, tT);        // tail: k in [384,512)
    }
    buf ^= 1;
  }
#undef COMPUTE

#pragma unroll
  for (int i = 0; i < 4; ++i) {
    const size_t row = (size_t)(bm + ty * 4 + i);
    f32x4 L, H;
#pragma unroll
    for (int j = 0; j < 4; ++j) {
      L[j] = __fadd_rn(__fadd_rn(xH[i][j], xT[i][j]),
                       __fadd_rn(tH[i][j], tT[i][j]));
      H[j] = __fadd_rn(__fadd_rn(xH[i][4 + j], xT[i][4 + j]),
                       __fadd_rn(tH[i][4 + j], tT[i][4 + j]));
    }
    *(f32x4*)&CUR[row * COUT + bn + tx * 4] = L;
    *(f32x4*)&CUR[row * COUT + bn + 64 + tx * 4] = H;
  }
}

// ---------------------------------------------------------------------------
// f32 LIF chain (np-exact): v = fl(fl(AL*v)+fl(BL*cur)); s=(v-1>0); reset.
// spikes {0,1}; rates = count/500.   [proven R13]
// ---------------------------------------------------------------------------
__global__ __launch_bounds__(256) void lif32(
    const float* __restrict__ CUR, float* __restrict__ spikes,
    float* __restrict__ rates) {
  const int j = blockIdx.x * 256 + threadIdx.x;  // b*512 + n
  const float AL = (float)AL64, BL = (float)BL64;
  float v = 0.0f;
  int cnt = 0;
#pragma unroll 10
  for (int t = 0; t < TSTEPS; ++t) {
    float cur = CUR[(size_t)t * SNEUR + j];
    v = __fadd_rn(__fmul_rn(AL, v), __fmul_rn(BL, cur));
    int sp = __fadd_rn(v, -1.0f) > 0.0f;
    cnt += sp;
    spikes[(size_t)t * SNEUR + j] = sp ? 1.0f : 0.0f;
    v = sp ? 0.0f : v;
  }
  rates[j] = __fdiv_rn((float)cnt, 500.0f);
}

extern "C" void kernel_launch(void* const* d_in, const int* in_sizes, int n_in,
                              void* d_out, int out_size, void* d_ws, size_t ws_size,
                              hipStream_t stream) {
  float* out = (float*)d_out;  // f32: spikes [500*64*512] ++ rates [64*512]

  float flag = 0.0f;
  const float* X = nullptr;
  const float* W = nullptr;
  const float* AP = nullptr;
  if (n_in != 3) {
    flag = 11.0f;
  } else {
    for (int i = 0; i < 3; ++i) {
      if (in_sizes[i] == 16384000) X = (const float*)d_in[i];
      else if (in_sizes[i] == 262144) W = (const float*)d_in[i];
      else if (in_sizes[i] == 1) AP = (const float*)d_in[i];
    }
    if (!X || !W || !AP) flag = 13.0f;
    else if (out_size != (int)OUTN) flag = 17.0f;
    else if (ws_size < 2ull * MTOT * CIN * 4ull) flag = 23.0f;
  }
  if (flag != 0.0f) {
    fill_const_f32<<<dim3(2048), dim3(256), 0, stream>>>(out, OUTN, flag);
    return;
  }

  float* TR = (float*)d_ws;                 // trace [32000,512] f32
  float* CUR = TR + (size_t)MTOT * CIN;     // current [32000,512] f32

  trace32<<<dim3(NCH / 256), dim3(256), 0, stream>>>(X, TR, AP);
  dim3 gg(COUT / 128, MTOT / 64);  // (4, 500)
  gemm_fused2<<<gg, dim3(256), 0, stream>>>(X, TR, W, CUR);
  lif32<<<dim3(SNEUR / 256), dim3(256), 0, stream>>>(
      CUR, out, out + (size_t)TSTEPS * SNEUR);
}

// Round 15
// 554.785 us; speedup vs baseline: 1.4017x; 1.4017x over previous
//
#include <hip/hip_runtime.h>

typedef float f32x4 __attribute__((ext_vector_type(4)));

#define TSTEPS 500
#define BDIM 64
#define CIN 512
#define COUT 512
#define MTOT (TSTEPS * BDIM)   // 32000
#define NCH (BDIM * CIN)       // 32768
#define SNEUR (BDIM * COUT)    // 32768
#define OUTN ((size_t)TSTEPS * SNEUR + SNEUR)

#define AL64 0.95122942450071400909   // math.exp(-0.001/0.02), f64
#define BL64 (1.0 - AL64)

__global__ __launch_bounds__(256) void fill_const_f32(
    float* __restrict__ p, size_t n, float c) {
  size_t i = (size_t)blockIdx.x * 256 + threadIdx.x;
  const size_t stride = (size_t)gridDim.x * 256;
  for (; i < n; i += stride) p[i] = c;
}

__device__ __forceinline__ void gll16(const float* g, float* l) {
  __builtin_amdgcn_global_load_lds(
      (const __attribute__((address_space(1))) void*)g,
      (__attribute__((address_space(3))) void*)l, 16, 0, 0);
}

// ---------------------------------------------------------------------------
// f32 trace scan (np-exact): tr = fl(fl(a*tr) + x)   [proven R13]
// ---------------------------------------------------------------------------
__global__ __launch_bounds__(256) void trace32(
    const float* __restrict__ X, float* __restrict__ TR,
    const float* __restrict__ alpha) {
  const int j = blockIdx.x * 256 + threadIdx.x;  // b*512 + ci
  const float a = fminf(fmaxf(alpha[0], 0.0f), 0.9999f);
  float tr = 0.0f;
#pragma unroll 10
  for (int t = 0; t < TSTEPS; ++t) {
    float x = X[(size_t)t * NCH + j];
    tr = __fadd_rn(__fmul_rn(a, tr), x);
    TR[(size_t)t * NCH + j] = tr;
  }
}

// ---------------------------------------------------------------------------
// Fused CUR = (X@W) + (TR@W); reduction order IDENTICAL to R13/R14 (head
// chain k<384, tail chain k>=384, combine fadd(fadd(xH,xT), fadd(tH,tT))).
// Structure: 64x64 tile (R13's proven 64-acc footprint, VGPR-safe) +
// R14's proven staging: double-buffered LDS via global_load_lds(16B),
// A k-groups XOR-swizzled on the GLOBAL source (linear LDS dest, rule #21),
// un-swizzled on the LDS read (verified conflict-free: R14 SQ_LDS_BANK=0).
// ---------------------------------------------------------------------------
__global__ __launch_bounds__(256) void gemm_fused3(
    const float* __restrict__ X, const float* __restrict__ TR,
    const float* __restrict__ W, float* __restrict__ CUR) {
  __shared__ __align__(16) float Ax[2][1024];  // [buf][64 rows x 16 k]
  __shared__ __align__(16) float At[2][1024];
  __shared__ __align__(16) float Bs[2][1024];  // [buf][16 k x 64 n]
  const int tid = threadIdx.x;
  const int ty = tid >> 4, tx = tid & 15;  // out: rows ty*4.., cols tx*4..
  const int bm = blockIdx.y * 64, bn = blockIdx.x * 64;
  const int wb = (tid & 192) * 4;  // wave-uniform LDS float offset

  // staging sources (per-lane 16B); A source pre-swizzled by k-group
  const int arow = tid >> 2, ag = tid & 3;
  const int ags = ag ^ ((arow >> 2) & 3);
  const float* sx = X + (size_t)(bm + arow) * CIN + ags * 4;
  const float* st = TR + (size_t)(bm + arow) * CIN + ags * 4;
  const int brow = tid >> 4, bcol = (tid & 15) * 4;
  const float* sb = W + (size_t)brow * COUT + bn + bcol;

  float xH[4][4] = {{0.0f}}, xT[4][4] = {{0.0f}};
  float tH[4][4] = {{0.0f}}, tT[4][4] = {{0.0f}};

  auto stage = [&](int b) {
    gll16(sx, &Ax[b][wb]);
    gll16(st, &At[b][wb]);
    gll16(sb, &Bs[b][wb]);
    sx += 16;            // next 16 k
    st += 16;
    sb += 16 * COUT;     // next 16 k rows
  };

  const int sw = ty & 3;  // A read-side un-swizzle ((row>>2)&3 == ty&3)

#define COMPUTE(b, AX, AT)                                                  \
  {                                                                         \
    const float* axp = Ax[b];                                               \
    const float* atp = At[b];                                               \
    const float* bsp = Bs[b];                                               \
    _Pragma("unroll") for (int kg = 0; kg < 4; ++kg) {                      \
      const int G = (kg ^ sw) * 4;                                          \
      f32x4 avx[4], avt[4];                                                 \
      _Pragma("unroll") for (int i = 0; i < 4; ++i) {                       \
        avx[i] = *(const f32x4*)&axp[(ty * 4 + i) * 16 + G];                \
        avt[i] = *(const f32x4*)&atp[(ty * 4 + i) * 16 + G];                \
      }                                                                     \
      _Pragma("unroll") for (int k2 = 0; k2 < 4; ++k2) {                    \
        f32x4 b4 = *(const f32x4*)&bsp[(kg * 4 + k2) * 64 + tx * 4];        \
        _Pragma("unroll") for (int i = 0; i < 4; ++i)                       \
          _Pragma("unroll") for (int j = 0; j < 4; ++j) {                   \
            AX[i][j] = fmaf(avx[i][k2], b4[j], AX[i][j]);                   \
            AT[i][j] = fmaf(avt[i][k2], b4[j], AT[i][j]);                   \
          }                                                                 \
      }                                                                     \
    }                                                                       \
  }

  stage(0);
  int buf = 0;
  for (int kt = 0; kt < 32; ++kt) {
    __syncthreads();              // drains vmcnt -> buf[buf] staged
    if (kt < 31) stage(buf ^ 1);  // async prefetch next tile during compute
    if (kt < 24) {
      COMPUTE(buf, xH, tH);       // head: k in [0,384)
    } else {
      COMPUTE(buf, xT, tT);       // tail: k in [384,512)
    }
    buf ^= 1;
  }
#undef COMPUTE

#pragma unroll
  for (int i = 0; i < 4; ++i) {
    const size_t row = (size_t)(bm + ty * 4 + i);
    f32x4 v;
#pragma unroll
    for (int j = 0; j < 4; ++j)
      v[j] = __fadd_rn(__fadd_rn(xH[i][j], xT[i][j]),
                       __fadd_rn(tH[i][j], tT[i][j]));
    *(f32x4*)&CUR[row * COUT + bn + tx * 4] = v;
  }
}

// ---------------------------------------------------------------------------
// f32 LIF chain (np-exact): v = fl(fl(AL*v)+fl(BL*cur)); s=(v-1>0); reset.
// spikes {0,1}; rates = count/500.   [proven R13]
// ---------------------------------------------------------------------------
__global__ __launch_bounds__(256) void lif32(
    const float* __restrict__ CUR, float* __restrict__ spikes,
    float* __restrict__ rates) {
  const int j = blockIdx.x * 256 + threadIdx.x;  // b*512 + n
  const float AL = (float)AL64, BL = (float)BL64;
  float v = 0.0f;
  int cnt = 0;
#pragma unroll 10
  for (int t = 0; t < TSTEPS; ++t) {
    float cur = CUR[(size_t)t * SNEUR + j];
    v = __fadd_rn(__fmul_rn(AL, v), __fmul_rn(BL, cur));
    int sp = __fadd_rn(v, -1.0f) > 0.0f;
    cnt += sp;
    spikes[(size_t)t * SNEUR + j] = sp ? 1.0f : 0.0f;
    v = sp ? 0.0f : v;
  }
  rates[j] = __fdiv_rn((float)cnt, 500.0f);
}

extern "C" void kernel_launch(void* const* d_in, const int* in_sizes, int n_in,
                              void* d_out, int out_size, void* d_ws, size_t ws_size,
                              hipStream_t stream) {
  float* out = (float*)d_out;  // f32: spikes [500*64*512] ++ rates [64*512]

  float flag = 0.0f;
  const float* X = nullptr;
  const float* W = nullptr;
  const float* AP = nullptr;
  if (n_in != 3) {
    flag = 11.0f;
  } else {
    for (int i = 0; i < 3; ++i) {
      if (in_sizes[i] == 16384000) X = (const float*)d_in[i];
      else if (in_sizes[i] == 262144) W = (const float*)d_in[i];
      else if (in_sizes[i] == 1) AP = (const float*)d_in[i];
    }
    if (!X || !W || !AP) flag = 13.0f;
    else if (out_size != (int)OUTN) flag = 17.0f;
    else if (ws_size < 2ull * MTOT * CIN * 4ull) flag = 23.0f;
  }
  if (flag != 0.0f) {
    fill_const_f32<<<dim3(2048), dim3(256), 0, stream>>>(out, OUTN, flag);
    return;
  }

  float* TR = (float*)d_ws;                 // trace [32000,512] f32
  float* CUR = TR + (size_t)MTOT * CIN;     // current [32000,512] f32

  trace32<<<dim3(NCH / 256), dim3(256), 0, stream>>>(X, TR, AP);
  dim3 gg(COUT / 64, MTOT / 64);  // (8, 500)
  gemm_fused3<<<gg, dim3(256), 0, stream>>>(X, TR, W, CUR);
  lif32<<<dim3(SNEUR / 256), dim3(256), 0, stream>>>(
      CUR, out, out + (size_t)TSTEPS * SNEUR);
}